// Round 1
// baseline (647.361 us; speedup 1.0000x reference)
//
#include <hip/hip_runtime.h>

#define HID 128  // both IN_DIM and hidden dim are 128

// ---------------------------------------------------------------------------
// Degree histogram: out_cnt[src[e]]++, in_cnt[dst[e]]++
// ---------------------------------------------------------------------------
__global__ void hist_kernel(const int* __restrict__ src, const int* __restrict__ dst,
                            int* __restrict__ out_cnt, int* __restrict__ in_cnt, int E) {
  int e = blockIdx.x * blockDim.x + threadIdx.x;
  if (e < E) {
    atomicAdd(&out_cnt[src[e]], 1);
    atomicAdd(&in_cnt[dst[e]], 1);
  }
}

// ---------------------------------------------------------------------------
// Hierarchical exclusive scan of in_cnt -> row_start (nb = ceil(n/256) <= 256)
// ---------------------------------------------------------------------------
__global__ void scan1_kernel(const int* __restrict__ cnt, int* __restrict__ row_start,
                             int* __restrict__ bsum, int n) {
  __shared__ int lds[256];
  int t = threadIdx.x;
  int i = blockIdx.x * 256 + t;
  int v = (i < n) ? cnt[i] : 0;
  lds[t] = v;
  __syncthreads();
  for (int off = 1; off < 256; off <<= 1) {
    int x = (t >= off) ? lds[t - off] : 0;
    __syncthreads();
    lds[t] += x;
    __syncthreads();
  }
  if (i < n) row_start[i] = lds[t] - v;   // exclusive within block
  if (t == 255) bsum[blockIdx.x] = lds[255];
}

__global__ void scan2_kernel(const int* __restrict__ bsum, int* __restrict__ boff, int nb) {
  __shared__ int lds[256];
  int t = threadIdx.x;
  int v = (t < nb) ? bsum[t] : 0;
  lds[t] = v;
  __syncthreads();
  for (int off = 1; off < 256; off <<= 1) {
    int x = (t >= off) ? lds[t - off] : 0;
    __syncthreads();
    lds[t] += x;
    __syncthreads();
  }
  boff[t] = lds[t] - v;                   // exclusive block offsets
}

__global__ void scan3_kernel(int* __restrict__ row_start, const int* __restrict__ boff,
                             const int* __restrict__ out_cnt, const int* __restrict__ in_cnt,
                             float* __restrict__ ns, float* __restrict__ nd, int n) {
  int i = blockIdx.x * 256 + threadIdx.x;
  if (i < n) {
    row_start[i] += boff[blockIdx.x];
    ns[i] = rsqrtf((float)max(out_cnt[i], 1));  // norm='both', clamp deg>=1
    nd[i] = rsqrtf((float)max(in_cnt[i], 1));
  }
}

// ---------------------------------------------------------------------------
// CSR fill (order within a row is arbitrary; fp32 sum tolerance is loose)
// ---------------------------------------------------------------------------
__global__ void fill_kernel(const int* __restrict__ src, const int* __restrict__ dst,
                            const int* __restrict__ row_start, int* __restrict__ fill_cnt,
                            int* __restrict__ csr, int E) {
  int e = blockIdx.x * blockDim.x + threadIdx.x;
  if (e < E) {
    int d = dst[e];
    int p = row_start[d] + atomicAdd(&fill_cnt[d], 1);
    csr[p] = src[e];
  }
}

// ---------------------------------------------------------------------------
// h = attr (float4 copy), then overwrite masked rows with the mask token
// ---------------------------------------------------------------------------
__global__ void copy_kernel(const float* __restrict__ a, float* __restrict__ h, int n4) {
  int i = blockIdx.x * blockDim.x + threadIdx.x;
  if (i < n4) ((float4*)h)[i] = ((const float4*)a)[i];
}

__global__ void mask_kernel(float* __restrict__ h, const int* __restrict__ mask,
                            const float* __restrict__ token, int n4) {
  int i = blockIdx.x * blockDim.x + threadIdx.x;
  if (i < n4) {
    int r = i >> 5, c4 = i & 31;       // 32 float4 per 128-wide row
    ((float4*)h)[(size_t)mask[r] * 32 + c4] = ((const float4*)token)[c4];
  }
}

// ---------------------------------------------------------------------------
// GEMM: out[M x 128] = A[M x 128] @ W[128 x 128], optional per-row scale
// (norm_src), optional per-col bias (decoder), optional row gather (decoder).
// Tile 64x64, 256 threads. As padded to stride 132 (row-broadcast lands on 2
// banks -> free 2-way). B staged in two 16KB halves: LDS = 49.8KB, 3 blk/CU.
// ---------------------------------------------------------------------------
__global__ __launch_bounds__(256) void gemm_kernel(
    const float* __restrict__ A, const float* __restrict__ W, float* __restrict__ out,
    const float* __restrict__ row_scale, const float* __restrict__ col_bias,
    const int* __restrict__ gather, int M) {
  __shared__ float As[64 * 132];
  __shared__ float Bs[64 * 64];
  const int t = threadIdx.x;
  const int m0 = blockIdx.x * 64;
  const int n0 = blockIdx.y * 64;

  // Stage A: 64 rows x 128 cols -> padded stride 132 (row byte stride 528, 16B-aligned)
#pragma unroll
  for (int i = 0; i < 8; ++i) {
    int idx4 = t + i * 256;            // 0..2047, 32 float4 per row
    int r = idx4 >> 5, c4 = idx4 & 31;
    int gm = m0 + r;
    float4 v = make_float4(0.f, 0.f, 0.f, 0.f);
    if (gm < M) {
      int row = gather ? gather[gm] : gm;
      v = *(const float4*)(A + (size_t)row * HID + c4 * 4);
    }
    *(float4*)(As + r * 132 + c4 * 4) = v;
  }

  const int tx = t & 15;  // cols n0 + tx*4 .. +3
  const int ty = t >> 4;  // rows ty*4 .. +3
  float4 acc[4];
#pragma unroll
  for (int r = 0; r < 4; ++r) acc[r] = make_float4(0.f, 0.f, 0.f, 0.f);

  for (int half = 0; half < 2; ++half) {
    __syncthreads();  // (half 0) As staged; (half 1) Bs readers done
#pragma unroll
    for (int i = 0; i < 4; ++i) {
      int idx4 = t + i * 256;          // 0..1023, 16 float4 per row
      int r = idx4 >> 4, c4 = idx4 & 15;
      *(float4*)(Bs + r * 64 + c4 * 4) =
          *(const float4*)(W + (size_t)(half * 64 + r) * HID + n0 + c4 * 4);
    }
    __syncthreads();
#pragma unroll
    for (int k = 0; k < 64; k += 4) {
      float4 b0 = *(const float4*)(Bs + (k + 0) * 64 + tx * 4);
      float4 b1 = *(const float4*)(Bs + (k + 1) * 64 + tx * 4);
      float4 b2 = *(const float4*)(Bs + (k + 2) * 64 + tx * 4);
      float4 b3 = *(const float4*)(Bs + (k + 3) * 64 + tx * 4);
#pragma unroll
      for (int r = 0; r < 4; ++r) {
        float4 a = *(const float4*)(As + (ty * 4 + r) * 132 + half * 64 + k);
        acc[r].x += a.x * b0.x + a.y * b1.x + a.z * b2.x + a.w * b3.x;
        acc[r].y += a.x * b0.y + a.y * b1.y + a.z * b2.y + a.w * b3.y;
        acc[r].z += a.x * b0.z + a.y * b1.z + a.z * b2.z + a.w * b3.z;
        acc[r].w += a.x * b0.w + a.y * b1.w + a.z * b2.w + a.w * b3.w;
      }
    }
  }

  float4 cb = make_float4(0.f, 0.f, 0.f, 0.f);
  if (col_bias) cb = *(const float4*)(col_bias + n0 + tx * 4);
#pragma unroll
  for (int r = 0; r < 4; ++r) {
    int gm = m0 + ty * 4 + r;
    if (gm < M) {
      float rs = row_scale ? row_scale[gm] : 1.f;
      float4 v;
      v.x = acc[r].x * rs + cb.x;
      v.y = acc[r].y * rs + cb.y;
      v.z = acc[r].z * rs + cb.z;
      v.w = acc[r].w * rs + cb.w;
      *(float4*)(out + (size_t)gm * HID + n0 + tx * 4) = v;
    }
  }
}

// ---------------------------------------------------------------------------
// CSR aggregation: one wave per dst node, lane l holds channels 2l,2l+1.
// h[v] = relu(nd[v] * sum_{e in CSR(v)} t[src_e] + bias). Atomic-free.
// ---------------------------------------------------------------------------
__global__ __launch_bounds__(256) void agg_kernel(
    const float* __restrict__ tin, const int* __restrict__ csr,
    const int* __restrict__ row_start, const int* __restrict__ in_cnt,
    const float* __restrict__ nd, const float* __restrict__ bias,
    float* __restrict__ hout, int n) {
  int node = (blockIdx.x * blockDim.x + threadIdx.x) >> 6;
  int lane = threadIdx.x & 63;
  if (node >= n) return;
  int beg = row_start[node];
  int cnt = in_cnt[node];
  const float2* tp = (const float2*)tin;
  float2 acc = make_float2(0.f, 0.f);
  int i = 0;
  for (; i + 4 <= cnt; i += 4) {  // 4-edge unroll for MLP (index loads then row loads)
    int s0 = csr[beg + i + 0];
    int s1 = csr[beg + i + 1];
    int s2 = csr[beg + i + 2];
    int s3 = csr[beg + i + 3];
    float2 v0 = tp[(size_t)s0 * 64 + lane];
    float2 v1 = tp[(size_t)s1 * 64 + lane];
    float2 v2 = tp[(size_t)s2 * 64 + lane];
    float2 v3 = tp[(size_t)s3 * 64 + lane];
    acc.x += v0.x + v1.x + v2.x + v3.x;
    acc.y += v0.y + v1.y + v2.y + v3.y;
  }
  for (; i < cnt; ++i) {
    int s = csr[beg + i];
    float2 v = tp[(size_t)s * 64 + lane];
    acc.x += v.x;
    acc.y += v.y;
  }
  float nv = nd[node];
  float2 b = ((const float2*)bias)[lane];
  float2 o;
  o.x = fmaxf(fmaf(acc.x, nv, b.x), 0.f);
  o.y = fmaxf(fmaf(acc.y, nv, b.y), 0.f);
  ((float2*)hout)[(size_t)node * 64 + lane] = o;
}

// ---------------------------------------------------------------------------
// Loss: mean((recon - attr[mask])^2); each block atomically adds its scaled
// partial into d_out[0] (d_out zeroed by memset at launch start).
// ---------------------------------------------------------------------------
__global__ __launch_bounds__(256) void loss_kernel(
    const float* __restrict__ recon, const float* __restrict__ attr,
    const int* __restrict__ mask, float* __restrict__ out, int n4, float scale) {
  int i = blockIdx.x * blockDim.x + threadIdx.x;
  float part = 0.f;
  if (i < n4) {
    int r = i >> 5, c4 = i & 31;
    float4 rv = ((const float4*)recon)[i];
    float4 av = *(const float4*)(attr + (size_t)mask[r] * HID + c4 * 4);
    float dx = rv.x - av.x, dy = rv.y - av.y, dz = rv.z - av.z, dw = rv.w - av.w;
    part = dx * dx + dy * dy + dz * dz + dw * dw;
  }
#pragma unroll
  for (int off = 32; off > 0; off >>= 1) part += __shfl_down(part, off);
  __shared__ float wsum[4];
  int lane = threadIdx.x & 63, w = threadIdx.x >> 6;
  if (lane == 0) wsum[w] = part;
  __syncthreads();
  if (threadIdx.x == 0) {
    float s = (wsum[0] + wsum[1]) + (wsum[2] + wsum[3]);
    atomicAdd(out, s * scale);
  }
}

// ---------------------------------------------------------------------------
extern "C" void kernel_launch(void* const* d_in, const int* in_sizes, int n_in,
                              void* d_out, int out_size, void* d_ws, size_t ws_size,
                              hipStream_t stream) {
  const float* attr  = (const float*)d_in[0];
  const int*   src   = (const int*)d_in[1];
  const int*   dst   = (const int*)d_in[2];
  const float* Ws    = (const float*)d_in[3];
  const float* bs    = (const float*)d_in[4];
  const float* decW  = (const float*)d_in[5];
  const float* decb  = (const float*)d_in[6];
  const float* token = (const float*)d_in[7];
  const int*   mask  = (const int*)d_in[8];

  const int N  = in_sizes[0] / HID;   // 50000
  const int E  = in_sizes[1];         // 800000
  const int NM = in_sizes[8];         // 15000

  // Workspace layout (all 16B-aligned; total ~55.6 MB)
  char* w = (char*)d_ws;
  float* h = (float*)w;        w += (size_t)N * HID * 4;
  float* t = (float*)w;        w += (size_t)N * HID * 4;   // also recon buffer
  int* csr = (int*)w;          w += (size_t)E * 4;
  int* row_start = (int*)w;    w += (size_t)N * 4;
  int* out_cnt = (int*)w;      w += (size_t)N * 4;  // | these three are
  int* in_cnt = (int*)w;       w += (size_t)N * 4;  // | contiguous: one
  int* fill_cnt = (int*)w;     w += (size_t)N * 4;  // | memset covers all
  float* ns = (float*)w;       w += (size_t)N * 4;
  float* nd = (float*)w;       w += (size_t)N * 4;
  int* bsum = (int*)w;         w += 256 * 4;
  int* boff = (int*)w;         w += 256 * 4;

  hipMemsetAsync(d_out, 0, sizeof(float), stream);
  hipMemsetAsync(out_cnt, 0, (size_t)3 * N * 4, stream);  // out/in/fill counters

  int eb = (E + 255) / 256;
  int nb = (N + 255) / 256;  // 196 <= 256: scan2 single block is valid

  hist_kernel<<<eb, 256, 0, stream>>>(src, dst, out_cnt, in_cnt, E);
  scan1_kernel<<<nb, 256, 0, stream>>>(in_cnt, row_start, bsum, N);
  scan2_kernel<<<1, 256, 0, stream>>>(bsum, boff, nb);
  scan3_kernel<<<nb, 256, 0, stream>>>(row_start, boff, out_cnt, in_cnt, ns, nd, N);
  fill_kernel<<<eb, 256, 0, stream>>>(src, dst, row_start, fill_cnt, csr, E);

  copy_kernel<<<(N * 32 + 255) / 256, 256, 0, stream>>>(attr, h, N * 32);
  mask_kernel<<<(NM * 32 + 255) / 256, 256, 0, stream>>>(h, mask, token, NM * 32);

  for (int l = 0; l < 3; ++l) {
    // t = (h @ W_l) * norm_src  (row scale fused into epilogue)
    gemm_kernel<<<dim3((N + 63) / 64, 2), 256, 0, stream>>>(
        h, Ws + (size_t)l * HID * HID, t, ns, nullptr, nullptr, N);
    // h = relu(agg(t) * norm_dst + b_l)
    agg_kernel<<<(N + 3) / 4, 256, 0, stream>>>(
        t, csr, row_start, in_cnt, nd, bs + (size_t)l * HID, h, N);
  }

  // recon(masked rows only) = h[mask] @ decW + decb  -> t
  gemm_kernel<<<dim3((NM + 63) / 64, 2), 256, 0, stream>>>(
      h, decW, t, nullptr, decb, mask, NM);
  loss_kernel<<<(NM * 32 + 255) / 256, 256, 0, stream>>>(
      t, attr, mask, (float*)d_out, NM * 32, 1.f / ((float)NM * HID));
}

// Round 2
// 533.563 us; speedup vs baseline: 1.2133x; 1.2133x over previous
//
#include <hip/hip_runtime.h>

#define HID 128  // both IN_DIM and hidden dim are 128

// ---------------------------------------------------------------------------
// Degree histogram: out_cnt[src[e]]++, in_cnt[dst[e]]++
// ---------------------------------------------------------------------------
__global__ void hist_kernel(const int* __restrict__ src, const int* __restrict__ dst,
                            int* __restrict__ out_cnt, int* __restrict__ in_cnt, int E) {
  int e = blockIdx.x * blockDim.x + threadIdx.x;
  if (e < E) {
    atomicAdd(&out_cnt[src[e]], 1);
    atomicAdd(&in_cnt[dst[e]], 1);
  }
}

// ---------------------------------------------------------------------------
// Hierarchical exclusive scan of in_cnt -> row_start (nb = ceil(n/256) <= 256)
// ---------------------------------------------------------------------------
__global__ void scan1_kernel(const int* __restrict__ cnt, int* __restrict__ row_start,
                             int* __restrict__ bsum, int n) {
  __shared__ int lds[256];
  int t = threadIdx.x;
  int i = blockIdx.x * 256 + t;
  int v = (i < n) ? cnt[i] : 0;
  lds[t] = v;
  __syncthreads();
  for (int off = 1; off < 256; off <<= 1) {
    int x = (t >= off) ? lds[t - off] : 0;
    __syncthreads();
    lds[t] += x;
    __syncthreads();
  }
  if (i < n) row_start[i] = lds[t] - v;   // exclusive within block
  if (t == 255) bsum[blockIdx.x] = lds[255];
}

__global__ void scan2_kernel(const int* __restrict__ bsum, int* __restrict__ boff, int nb) {
  __shared__ int lds[256];
  int t = threadIdx.x;
  int v = (t < nb) ? bsum[t] : 0;
  lds[t] = v;
  __syncthreads();
  for (int off = 1; off < 256; off <<= 1) {
    int x = (t >= off) ? lds[t - off] : 0;
    __syncthreads();
    lds[t] += x;
    __syncthreads();
  }
  boff[t] = lds[t] - v;                   // exclusive block offsets
}

__global__ void scan3_kernel(int* __restrict__ row_start, const int* __restrict__ boff,
                             const int* __restrict__ out_cnt, const int* __restrict__ in_cnt,
                             float* __restrict__ ns, float* __restrict__ nd, int n) {
  int i = blockIdx.x * 256 + threadIdx.x;
  if (i < n) {
    row_start[i] += boff[blockIdx.x];
    ns[i] = rsqrtf((float)max(out_cnt[i], 1));  // norm='both', clamp deg>=1
    nd[i] = rsqrtf((float)max(in_cnt[i], 1));
  }
}

// ---------------------------------------------------------------------------
// CSR fill (order within a row is arbitrary; fp32 sum tolerance is loose)
// ---------------------------------------------------------------------------
__global__ void fill_kernel(const int* __restrict__ src, const int* __restrict__ dst,
                            const int* __restrict__ row_start, int* __restrict__ fill_cnt,
                            int* __restrict__ csr, int E) {
  int e = blockIdx.x * blockDim.x + threadIdx.x;
  if (e < E) {
    int d = dst[e];
    int p = row_start[d] + atomicAdd(&fill_cnt[d], 1);
    csr[p] = src[e];
  }
}

// ---------------------------------------------------------------------------
// h = attr (float4 copy), then overwrite masked rows with the mask token
// ---------------------------------------------------------------------------
__global__ void copy_kernel(const float* __restrict__ a, float* __restrict__ h, int n4) {
  int i = blockIdx.x * blockDim.x + threadIdx.x;
  if (i < n4) ((float4*)h)[i] = ((const float4*)a)[i];
}

__global__ void mask_kernel(float* __restrict__ h, const int* __restrict__ mask,
                            const float* __restrict__ token, int n4) {
  int i = blockIdx.x * blockDim.x + threadIdx.x;
  if (i < n4) {
    int r = i >> 5, c4 = i & 31;       // 32 float4 per 128-wide row
    ((float4*)h)[(size_t)mask[r] * 32 + c4] = ((const float4*)token)[c4];
  }
}

// ---------------------------------------------------------------------------
// GEMM: out[M x 128] = A[M x 128] @ W[128 x 128], optional per-row scale
// (norm_src), optional per-col bias (decoder), optional row gather (decoder).
//
// R1 redesign: 128x128 block tile, 256 threads, 8x8 micro-tile per thread
// (rows tm*4+{0..3} and +64, cols tn*4+{0..3} and +64 -- keeps every LDS
// read phase at <=2-way aliasing = free). A staged TRANSPOSED AsT[k][m]
// (stride 132) so outer-product A reads are 2x ds_read_b128; B [k][n] stride
// 128. 1 B of LDS per FMA (was 2) -- halves pressure on the per-CU LDS pipe,
// which R0 counters showed to be the bottleneck (VALUBusy 20%). K chunked by
// 32 with register prefetch of the next chunk issued before the barrier.
// LDS 33.3 KB.
// ---------------------------------------------------------------------------
__global__ __launch_bounds__(256, 2) void gemm_kernel(
    const float* __restrict__ A, const float* __restrict__ W, float* __restrict__ out,
    const float* __restrict__ row_scale, const float* __restrict__ col_bias,
    const int* __restrict__ gather, int M) {
  __shared__ float AsT[32 * 132];   // [k][m], stride 132: a-reads hit disjoint banks
  __shared__ float Bs[32 * 128];    // [k][n], stride 128: b-reads 2-way (free)
  const int t = threadIdx.x;
  const int m0 = blockIdx.x * 128;

  // --- staging roles ---
  const int rowL = t & 127;         // A: this thread stages row rowL ...
  const int kq0 = t >> 7;          // ... float4s kq0, kq0+2, kq0+4, kq0+6 of each chunk
  const int bk = t >> 5;            // B: rows bk, bk+8, bk+16, bk+24 of each chunk
  const int bc4 = t & 31;           // B: float4 column
  const int gmRow = m0 + rowL;
  const bool valid = gmRow < M;
  const int rowA = valid ? (gather ? gather[gmRow] : gmRow) : 0;
  const float* __restrict__ Arow = A + (size_t)rowA * HID;

  // --- compute roles ---
  const int tn = t & 15;            // cols tn*4..+3 and +64
  const int tm = t >> 4;            // rows tm*4..+3 and +64

  float acc[8][8];
#pragma unroll
  for (int r = 0; r < 8; ++r)
#pragma unroll
    for (int c = 0; c < 8; ++c) acc[r][c] = 0.f;

  float4 ra[4], rb[4];
  const float4 z4 = make_float4(0.f, 0.f, 0.f, 0.f);
#pragma unroll
  for (int i = 0; i < 4; ++i) {
    int kq = kq0 + 2 * i;
    ra[i] = valid ? *(const float4*)(Arow + kq * 4) : z4;
    rb[i] = *(const float4*)(W + (size_t)(bk + 8 * i) * HID + bc4 * 4);
  }

  for (int ch = 0; ch < 4; ++ch) {
    __syncthreads();                // previous chunk's LDS reads done
#pragma unroll
    for (int i = 0; i < 4; ++i) {
      int kq = kq0 + 2 * i;
      float* p = AsT + (kq * 4) * 132 + rowL;   // transpose: 4 scalar writes
      p[0 * 132] = ra[i].x;
      p[1 * 132] = ra[i].y;
      p[2 * 132] = ra[i].z;
      p[3 * 132] = ra[i].w;
      *(float4*)(Bs + (bk + 8 * i) * 128 + bc4 * 4) = rb[i];
    }
    if (ch < 3) {                   // prefetch next chunk; in flight during compute
      int k0n = (ch + 1) * 32;
#pragma unroll
      for (int i = 0; i < 4; ++i) {
        int kq = kq0 + 2 * i;
        ra[i] = valid ? *(const float4*)(Arow + k0n + kq * 4) : z4;
        rb[i] = *(const float4*)(W + (size_t)(k0n + bk + 8 * i) * HID + bc4 * 4);
      }
    }
    __syncthreads();                // staged data visible
#pragma unroll
    for (int k = 0; k < 32; ++k) {
      float4 a0 = *(const float4*)(AsT + k * 132 + tm * 4);
      float4 a1 = *(const float4*)(AsT + k * 132 + tm * 4 + 64);
      float4 b0 = *(const float4*)(Bs + k * 128 + tn * 4);
      float4 b1 = *(const float4*)(Bs + k * 128 + tn * 4 + 64);
      float av[8] = {a0.x, a0.y, a0.z, a0.w, a1.x, a1.y, a1.z, a1.w};
      float bv[8] = {b0.x, b0.y, b0.z, b0.w, b1.x, b1.y, b1.z, b1.w};
#pragma unroll
      for (int r = 0; r < 8; ++r)
#pragma unroll
        for (int c = 0; c < 8; ++c) acc[r][c] += av[r] * bv[c];
    }
  }

  float4 cb0 = z4, cb1 = z4;
  if (col_bias) {
    cb0 = *(const float4*)(col_bias + tn * 4);
    cb1 = *(const float4*)(col_bias + tn * 4 + 64);
  }
#pragma unroll
  for (int r = 0; r < 8; ++r) {
    int gm = m0 + tm * 4 + (r & 3) + (r >> 2) * 64;
    if (gm < M) {
      float rs = row_scale ? row_scale[gm] : 1.f;
      float4 v0, v1;
      v0.x = acc[r][0] * rs + cb0.x;
      v0.y = acc[r][1] * rs + cb0.y;
      v0.z = acc[r][2] * rs + cb0.z;
      v0.w = acc[r][3] * rs + cb0.w;
      v1.x = acc[r][4] * rs + cb1.x;
      v1.y = acc[r][5] * rs + cb1.y;
      v1.z = acc[r][6] * rs + cb1.z;
      v1.w = acc[r][7] * rs + cb1.w;
      *(float4*)(out + (size_t)gm * HID + tn * 4) = v0;
      *(float4*)(out + (size_t)gm * HID + tn * 4 + 64) = v1;
    }
  }
}

// ---------------------------------------------------------------------------
// CSR aggregation: one wave per dst node, lane l holds channels 2l,2l+1.
// h[v] = relu(nd[v] * sum_{e in CSR(v)} t[src_e] + bias). Atomic-free.
// ---------------------------------------------------------------------------
__global__ __launch_bounds__(256) void agg_kernel(
    const float* __restrict__ tin, const int* __restrict__ csr,
    const int* __restrict__ row_start, const int* __restrict__ in_cnt,
    const float* __restrict__ nd, const float* __restrict__ bias,
    float* __restrict__ hout, int n) {
  int node = (blockIdx.x * blockDim.x + threadIdx.x) >> 6;
  int lane = threadIdx.x & 63;
  if (node >= n) return;
  int beg = row_start[node];
  int cnt = in_cnt[node];
  const float2* tp = (const float2*)tin;
  float2 acc = make_float2(0.f, 0.f);
  int i = 0;
  for (; i + 4 <= cnt; i += 4) {  // 4-edge unroll for MLP (index loads then row loads)
    int s0 = csr[beg + i + 0];
    int s1 = csr[beg + i + 1];
    int s2 = csr[beg + i + 2];
    int s3 = csr[beg + i + 3];
    float2 v0 = tp[(size_t)s0 * 64 + lane];
    float2 v1 = tp[(size_t)s1 * 64 + lane];
    float2 v2 = tp[(size_t)s2 * 64 + lane];
    float2 v3 = tp[(size_t)s3 * 64 + lane];
    acc.x += v0.x + v1.x + v2.x + v3.x;
    acc.y += v0.y + v1.y + v2.y + v3.y;
  }
  for (; i < cnt; ++i) {
    int s = csr[beg + i];
    float2 v = tp[(size_t)s * 64 + lane];
    acc.x += v.x;
    acc.y += v.y;
  }
  float nv = nd[node];
  float2 b = ((const float2*)bias)[lane];
  float2 o;
  o.x = fmaxf(fmaf(acc.x, nv, b.x), 0.f);
  o.y = fmaxf(fmaf(acc.y, nv, b.y), 0.f);
  ((float2*)hout)[(size_t)node * 64 + lane] = o;
}

// ---------------------------------------------------------------------------
// Loss: mean((recon - attr[mask])^2); each block atomically adds its scaled
// partial into d_out[0] (d_out zeroed by memset at launch start).
// ---------------------------------------------------------------------------
__global__ __launch_bounds__(256) void loss_kernel(
    const float* __restrict__ recon, const float* __restrict__ attr,
    const int* __restrict__ mask, float* __restrict__ out, int n4, float scale) {
  int i = blockIdx.x * blockDim.x + threadIdx.x;
  float part = 0.f;
  if (i < n4) {
    int r = i >> 5, c4 = i & 31;
    float4 rv = ((const float4*)recon)[i];
    float4 av = *(const float4*)(attr + (size_t)mask[r] * HID + c4 * 4);
    float dx = rv.x - av.x, dy = rv.y - av.y, dz = rv.z - av.z, dw = rv.w - av.w;
    part = dx * dx + dy * dy + dz * dz + dw * dw;
  }
#pragma unroll
  for (int off = 32; off > 0; off >>= 1) part += __shfl_down(part, off);
  __shared__ float wsum[4];
  int lane = threadIdx.x & 63, w = threadIdx.x >> 6;
  if (lane == 0) wsum[w] = part;
  __syncthreads();
  if (threadIdx.x == 0) {
    float s = (wsum[0] + wsum[1]) + (wsum[2] + wsum[3]);
    atomicAdd(out, s * scale);
  }
}

// ---------------------------------------------------------------------------
extern "C" void kernel_launch(void* const* d_in, const int* in_sizes, int n_in,
                              void* d_out, int out_size, void* d_ws, size_t ws_size,
                              hipStream_t stream) {
  const float* attr  = (const float*)d_in[0];
  const int*   src   = (const int*)d_in[1];
  const int*   dst   = (const int*)d_in[2];
  const float* Ws    = (const float*)d_in[3];
  const float* bs    = (const float*)d_in[4];
  const float* decW  = (const float*)d_in[5];
  const float* decb  = (const float*)d_in[6];
  const float* token = (const float*)d_in[7];
  const int*   mask  = (const int*)d_in[8];

  const int N  = in_sizes[0] / HID;   // 50000
  const int E  = in_sizes[1];         // 800000
  const int NM = in_sizes[8];         // 15000

  // Workspace layout (all 16B-aligned; total ~55.6 MB)
  char* w = (char*)d_ws;
  float* h = (float*)w;        w += (size_t)N * HID * 4;
  float* t = (float*)w;        w += (size_t)N * HID * 4;   // also recon buffer
  int* csr = (int*)w;          w += (size_t)E * 4;
  int* row_start = (int*)w;    w += (size_t)N * 4;
  int* out_cnt = (int*)w;      w += (size_t)N * 4;  // | these three are
  int* in_cnt = (int*)w;       w += (size_t)N * 4;  // | contiguous: one
  int* fill_cnt = (int*)w;     w += (size_t)N * 4;  // | memset covers all
  float* ns = (float*)w;       w += (size_t)N * 4;
  float* nd = (float*)w;       w += (size_t)N * 4;
  int* bsum = (int*)w;         w += 256 * 4;
  int* boff = (int*)w;         w += 256 * 4;

  hipMemsetAsync(d_out, 0, sizeof(float), stream);
  hipMemsetAsync(out_cnt, 0, (size_t)3 * N * 4, stream);  // out/in/fill counters

  int eb = (E + 255) / 256;
  int nb = (N + 255) / 256;  // 196 <= 256: scan2 single block is valid

  hist_kernel<<<eb, 256, 0, stream>>>(src, dst, out_cnt, in_cnt, E);
  scan1_kernel<<<nb, 256, 0, stream>>>(in_cnt, row_start, bsum, N);
  scan2_kernel<<<1, 256, 0, stream>>>(bsum, boff, nb);
  scan3_kernel<<<nb, 256, 0, stream>>>(row_start, boff, out_cnt, in_cnt, ns, nd, N);
  fill_kernel<<<eb, 256, 0, stream>>>(src, dst, row_start, fill_cnt, csr, E);

  copy_kernel<<<(N * 32 + 255) / 256, 256, 0, stream>>>(attr, h, N * 32);
  mask_kernel<<<(NM * 32 + 255) / 256, 256, 0, stream>>>(h, mask, token, NM * 32);

  for (int l = 0; l < 3; ++l) {
    // t = (h @ W_l) * norm_src  (row scale fused into epilogue)
    gemm_kernel<<<(N + 127) / 128, 256, 0, stream>>>(
        h, Ws + (size_t)l * HID * HID, t, ns, nullptr, nullptr, N);
    // h = relu(agg(t) * norm_dst + b_l)
    agg_kernel<<<(N + 3) / 4, 256, 0, stream>>>(
        t, csr, row_start, in_cnt, nd, bs + (size_t)l * HID, h, N);
  }

  // recon(masked rows only) = h[mask] @ decW + decb  -> t
  gemm_kernel<<<(NM + 127) / 128, 256, 0, stream>>>(
      h, decW, t, nullptr, decb, mask, NM);
  loss_kernel<<<(NM * 32 + 255) / 256, 256, 0, stream>>>(
      t, attr, mask, (float*)d_out, NM * 32, 1.f / ((float)NM * HID));
}